// Round 1
// baseline (177.020 us; speedup 1.0000x reference)
//
#include <hip/hip_runtime.h>
#include <hip/hip_bf16.h>

// Problem constants
#define TOK  4096      // tokens = 16*16*16
#define CH   384       // hidden
#define NH   6         // heads
#define HD   64        // head dim
#define NQKV 1152      // 3*CH

typedef __bf16 bf16x8 __attribute__((ext_vector_type(8)));
typedef float f32x4 __attribute__((ext_vector_type(4)));
typedef unsigned short u16x8 __attribute__((ext_vector_type(8)));

__device__ __forceinline__ unsigned short f2bf(float f) {
    unsigned int u = __builtin_bit_cast(unsigned int, f);
    u += 0x7FFFu + ((u >> 16) & 1u);   // round-to-nearest-even
    return (unsigned short)(u >> 16);
}

__device__ __forceinline__ f32x4 mfma_bf16(u16x8 a, u16x8 b, f32x4 c) {
    return __builtin_amdgcn_mfma_f32_16x16x32_bf16(
        __builtin_bit_cast(bf16x8, a), __builtin_bit_cast(bf16x8, b), c, 0, 0, 0);
}

// ---------------------------------------------------------------------------
// Kernel 1: qkv = xt @ W_qkv.   A = xt[t][c] (x stored [c][t]), B = W_qkv[c][n]
// Writes: Q (scaled by 0.125) [h][t][64] bf16, K [h][t][64] bf16, V^T [h][64][t] bf16
// Tile: BM=64 (tokens) x BN=64 (channels) x BK=32; 4 waves in 2x2.
// Each blockIdx.y covers exactly one head-section of one of q/k/v.
// ---------------------------------------------------------------------------
__global__ __launch_bounds__(256) void qkv_kernel(
    const float* __restrict__ x, const float* __restrict__ w,
    unsigned short* __restrict__ qws, unsigned short* __restrict__ kws,
    unsigned short* __restrict__ vtws)
{
    __shared__ __align__(16) unsigned short As[64][32];   // [m][k]
    __shared__ __align__(16) unsigned short Bs[64][32];   // [n][k]
    const int tid = threadIdx.x;
    const int t0 = blockIdx.x * 64;
    const int by = blockIdx.y;            // 0..17
    const int n0 = by * 64;
    const int lane = tid & 63;
    const int wid  = tid >> 6;
    const int wr = wid >> 1, wc = wid & 1;
    const int l15 = lane & 15, lg = lane >> 4;
    const int sm  = tid & 63;             // staging m/n index
    const int skg = tid >> 6;             // staging k-group (8 k's each)

    f32x4 acc[2][2] = {};

    for (int k0 = 0; k0 < CH; k0 += 32) {
        u16x8 av, bv;
        #pragma unroll
        for (int j = 0; j < 8; ++j) {
            // A: xt[t][k] = x[k*TOK + t]; coalesced along t (=sm) per j
            av[j] = f2bf(x[(k0 + skg*8 + j) * TOK + t0 + sm]);
            // B: w[k][n]; coalesced along n (=sm) per j
            bv[j] = f2bf(w[(k0 + skg*8 + j) * NQKV + n0 + sm]);
        }
        __syncthreads();   // previous iter's fragment reads done
        *reinterpret_cast<u16x8*>(&As[sm][skg*8]) = av;
        *reinterpret_cast<u16x8*>(&Bs[sm][skg*8]) = bv;
        __syncthreads();

        u16x8 afr[2], bfr[2];
        #pragma unroll
        for (int mi = 0; mi < 2; ++mi)
            afr[mi] = *reinterpret_cast<const u16x8*>(&As[wr*32 + mi*16 + l15][lg*8]);
        #pragma unroll
        for (int ni = 0; ni < 2; ++ni)
            bfr[ni] = *reinterpret_cast<const u16x8*>(&Bs[wc*32 + ni*16 + l15][lg*8]);
        #pragma unroll
        for (int mi = 0; mi < 2; ++mi)
            #pragma unroll
            for (int ni = 0; ni < 2; ++ni)
                acc[mi][ni] = mfma_bf16(afr[mi], bfr[ni], acc[mi][ni]);
    }

    // Epilogue. by: 0-5 -> Q (fold in softmax scale 1/8, exact in bf16),
    //               6-11 -> K, 12-17 -> V (stored transposed [d][t]).
    const float qscale = (by < 6) ? 0.125f : 1.0f;
    const int head = by % 6;
    #pragma unroll
    for (int mi = 0; mi < 2; ++mi)
    #pragma unroll
    for (int ni = 0; ni < 2; ++ni)
    #pragma unroll
    for (int r = 0; r < 4; ++r) {
        int t   = t0 + wr*32 + mi*16 + lg*4 + r;       // C/D: row=(lane>>4)*4+reg
        int dim = wc*32 + ni*16 + l15;                 //      col=lane&15
        unsigned short v = f2bf(acc[mi][ni][r] * qscale);
        if (by < 6)        qws[head*(TOK*HD) + t*HD + dim] = v;
        else if (by < 12)  kws[head*(TOK*HD) + t*HD + dim] = v;
        else               vtws[head*(TOK*HD) + dim*TOK + t] = v;
    }
}

// ---------------------------------------------------------------------------
// Kernel 2: flash attention. block = (q-tile of 64 rows, head). 4 waves, each
// owns 16 q-rows. Q frags in registers for the whole loop. K and V^T tiles
// staged in LDS with XOR chunk swizzle (chunk ^= row&7) to kill the 16-way
// bank conflict of row-major [64][64] bf16 reads. Softmax in exp2-domain
// (Q pre-scaled by 1/8; multiply logits by log2(e) in fp32).
// ---------------------------------------------------------------------------
__global__ __launch_bounds__(256) void attn_kernel(
    const unsigned short* __restrict__ qws, const unsigned short* __restrict__ kws,
    const unsigned short* __restrict__ vtws, unsigned short* __restrict__ ob)
{
    __shared__ __align__(16) unsigned short Ks[64][64];    // [ktok][d], swizzled
    __shared__ __align__(16) unsigned short Vts[64][64];   // [d][ktok], swizzled
    __shared__ __align__(16) unsigned short Ps[64][64];    // [qrow][ktok], swizzled
    const int tid = threadIdx.x;
    const int h  = blockIdx.y;
    const int q0 = blockIdx.x * 64;
    const int lane = tid & 63, wid = tid >> 6;
    const int l15 = lane & 15, lg = lane >> 4;
    const float LOG2E = 1.4426950408889634f;

    const unsigned short* qh = qws  + h*(TOK*HD);
    const unsigned short* kh = kws  + h*(TOK*HD);
    const unsigned short* vh = vtws + h*(TOK*HD);

    // Q fragments: wave's 16 rows, K-dim (=64) split into s=0,1
    u16x8 aq[2];
    #pragma unroll
    for (int s = 0; s < 2; ++s)
        aq[s] = *reinterpret_cast<const u16x8*>(
            &qh[(q0 + wid*16 + l15)*HD + s*32 + lg*8]);

    f32x4 oacc[4] = {};
    float mrow[4], lsum[4];
    #pragma unroll
    for (int r = 0; r < 4; ++r) { mrow[r] = -1e30f; lsum[r] = 0.f; }

    for (int kt = 0; kt < TOK; kt += 64) {
        __syncthreads();   // prev PV reads of Ks/Vts/Ps done
        #pragma unroll
        for (int i = 0; i < 2; ++i) {
            int e = tid + i*256;
            int row = e >> 3, ch = e & 7;
            int chs = ch ^ (row & 7);
            *reinterpret_cast<u16x8*>(&Ks[row][chs*8]) =
                *reinterpret_cast<const u16x8*>(&kh[(kt+row)*HD + ch*8]);
            *reinterpret_cast<u16x8*>(&Vts[row][chs*8]) =
                *reinterpret_cast<const u16x8*>(&vh[row*TOK + kt + ch*8]);
        }
        __syncthreads();

        // S = Q K^T  (A=Q, B[d][ktok]=K[ktok][d] read from row-major Ks)
        f32x4 sacc[4] = {};
        #pragma unroll
        for (int cf = 0; cf < 4; ++cf) {
            int row = cf*16 + l15;
            #pragma unroll
            for (int s = 0; s < 2; ++s) {
                int chs = (s*4 + lg) ^ (row & 7);
                u16x8 b = *reinterpret_cast<const u16x8*>(&Ks[row][chs*8]);
                sacc[cf] = mfma_bf16(aq[s], b, sacc[cf]);
            }
        }

        // online softmax, exp2 domain; rows = (lg*4 + r) within wave strip
        float sv[4][4];
        #pragma unroll
        for (int cf = 0; cf < 4; ++cf)
            #pragma unroll
            for (int r = 0; r < 4; ++r)
                sv[cf][r] = sacc[cf][r] * LOG2E;

        float tmax[4];
        #pragma unroll
        for (int r = 0; r < 4; ++r)
            tmax[r] = fmaxf(fmaxf(sv[0][r], sv[1][r]), fmaxf(sv[2][r], sv[3][r]));
        #pragma unroll
        for (int off = 1; off < 16; off <<= 1)
            #pragma unroll
            for (int r = 0; r < 4; ++r)
                tmax[r] = fmaxf(tmax[r], __shfl_xor(tmax[r], off, 64));

        float corr[4];
        #pragma unroll
        for (int r = 0; r < 4; ++r) {
            float mnew = fmaxf(mrow[r], tmax[r]);
            corr[r] = __builtin_amdgcn_exp2f(mrow[r] - mnew);
            mrow[r] = mnew;
        }
        float p[4][4], psum[4] = {0.f, 0.f, 0.f, 0.f};
        #pragma unroll
        for (int cf = 0; cf < 4; ++cf)
            #pragma unroll
            for (int r = 0; r < 4; ++r) {
                p[cf][r] = __builtin_amdgcn_exp2f(sv[cf][r] - mrow[r]);
                psum[r] += p[cf][r];
            }
        #pragma unroll
        for (int off = 1; off < 16; off <<= 1)
            #pragma unroll
            for (int r = 0; r < 4; ++r)
                psum[r] += __shfl_xor(psum[r], off, 64);
        #pragma unroll
        for (int r = 0; r < 4; ++r)
            lsum[r] = lsum[r]*corr[r] + psum[r];
        #pragma unroll
        for (int df = 0; df < 4; ++df)
            #pragma unroll
            for (int r = 0; r < 4; ++r)
                oacc[df][r] *= corr[r];

        // P -> LDS (bf16, swizzled). Written/read by the same wave, but keep a
        // barrier for guaranteed LDS write->read ordering in the baseline.
        #pragma unroll
        for (int cf = 0; cf < 4; ++cf)
            #pragma unroll
            for (int r = 0; r < 4; ++r) {
                int row = wid*16 + lg*4 + r;
                int col = cf*16 + l15;
                int idx = ((((col >> 3) ^ (row & 7)) << 3) | (col & 7));
                Ps[row][idx] = f2bf(p[cf][r]);
            }
        __syncthreads();

        // O += P V   (A=P from Ps, B[ktok][d]=V read from Vts[d][ktok] rows)
        u16x8 ap[2];
        {
            int prow = wid*16 + l15;
            #pragma unroll
            for (int s = 0; s < 2; ++s) {
                int chs = (s*4 + lg) ^ (prow & 7);
                ap[s] = *reinterpret_cast<const u16x8*>(&Ps[prow][chs*8]);
            }
        }
        #pragma unroll
        for (int df = 0; df < 4; ++df) {
            int vrow = df*16 + l15;
            #pragma unroll
            for (int s = 0; s < 2; ++s) {
                int chs = (s*4 + lg) ^ (vrow & 7);
                u16x8 bv = *reinterpret_cast<const u16x8*>(&Vts[vrow][chs*8]);
                oacc[df] = mfma_bf16(ap[s], bv, oacc[df]);
            }
        }
    }

    // normalize + write O as bf16 [t][CH] for the out-projection GEMM
    #pragma unroll
    for (int df = 0; df < 4; ++df)
        #pragma unroll
        for (int r = 0; r < 4; ++r) {
            int t = q0 + wid*16 + lg*4 + r;
            int d = df*16 + l15;
            ob[t*CH + h*HD + d] = f2bf(oacc[df][r] / lsum[r]);
        }
}

// ---------------------------------------------------------------------------
// Kernel 3: out = O @ W_out + b_out, fp32 result in [t][CH] flat order
// (== d_out layout: reference's final reshape is a raw view).
// ---------------------------------------------------------------------------
__global__ __launch_bounds__(256) void out_kernel(
    const unsigned short* __restrict__ ob, const float* __restrict__ w,
    const float* __restrict__ bias, float* __restrict__ out)
{
    __shared__ __align__(16) unsigned short As[64][32];
    __shared__ __align__(16) unsigned short Bs[64][32];
    const int tid = threadIdx.x;
    const int t0 = blockIdx.x * 64;
    const int n0 = blockIdx.y * 64;
    const int lane = tid & 63, wid = tid >> 6;
    const int wr = wid >> 1, wc = wid & 1;
    const int l15 = lane & 15, lg = lane >> 4;
    const int sm = tid & 63, skg = tid >> 6;

    f32x4 acc[2][2] = {};

    for (int k0 = 0; k0 < CH; k0 += 32) {
        u16x8 av = *reinterpret_cast<const u16x8*>(&ob[(t0+sm)*CH + k0 + skg*8]);
        u16x8 bv;
        #pragma unroll
        for (int j = 0; j < 8; ++j)
            bv[j] = f2bf(w[(k0 + skg*8 + j) * CH + n0 + sm]);
        __syncthreads();
        *reinterpret_cast<u16x8*>(&As[sm][skg*8]) = av;
        *reinterpret_cast<u16x8*>(&Bs[sm][skg*8]) = bv;
        __syncthreads();

        u16x8 afr[2], bfr[2];
        #pragma unroll
        for (int mi = 0; mi < 2; ++mi)
            afr[mi] = *reinterpret_cast<const u16x8*>(&As[wr*32 + mi*16 + l15][lg*8]);
        #pragma unroll
        for (int ni = 0; ni < 2; ++ni)
            bfr[ni] = *reinterpret_cast<const u16x8*>(&Bs[wc*32 + ni*16 + l15][lg*8]);
        #pragma unroll
        for (int mi = 0; mi < 2; ++mi)
            #pragma unroll
            for (int ni = 0; ni < 2; ++ni)
                acc[mi][ni] = mfma_bf16(afr[mi], bfr[ni], acc[mi][ni]);
    }

    #pragma unroll
    for (int mi = 0; mi < 2; ++mi)
    #pragma unroll
    for (int ni = 0; ni < 2; ++ni)
    #pragma unroll
    for (int r = 0; r < 4; ++r) {
        int t = t0 + wr*32 + mi*16 + lg*4 + r;
        int n = n0 + wc*32 + ni*16 + l15;
        out[t*CH + n] = acc[mi][ni][r] + bias[n];
    }
}

// ---------------------------------------------------------------------------
extern "C" void kernel_launch(void* const* d_in, const int* in_sizes, int n_in,
                              void* d_out, int out_size, void* d_ws, size_t ws_size,
                              hipStream_t stream) {
    const float* x    = (const float*)d_in[0];   // [384][4096] (c-major)
    const float* wqkv = (const float*)d_in[1];   // [384][1152]
    const float* wout = (const float*)d_in[2];   // [384][384]
    const float* bout = (const float*)d_in[3];   // [384]
    float* out = (float*)d_out;                  // [4096][384] flat

    // workspace (bf16): Q, K, V^T each 6*4096*64, O 4096*384  => 12.6 MB total
    unsigned short* ws  = (unsigned short*)d_ws;
    unsigned short* qp  = ws;
    unsigned short* kp  = qp + NH*TOK*HD;
    unsigned short* vtp = kp + NH*TOK*HD;
    unsigned short* op  = vtp + NH*TOK*HD;

    qkv_kernel<<<dim3(64, 18), 256, 0, stream>>>(x, wqkv, qp, kp, vtp);
    attn_kernel<<<dim3(64, 6), 256, 0, stream>>>(qp, kp, vtp, op);
    out_kernel<<<dim3(64, 6), 256, 0, stream>>>(op, wout, bout, out);
}

// Round 2
// 125.842 us; speedup vs baseline: 1.4067x; 1.4067x over previous
//
#include <hip/hip_runtime.h>
#include <hip/hip_bf16.h>

// Problem constants
#define TOK  4096      // tokens = 16*16*16
#define CH   384       // hidden
#define NH   6         // heads
#define HD   64        // head dim
#define NQKV 1152      // 3*CH

typedef __bf16 bf16x8 __attribute__((ext_vector_type(8)));
typedef float f32x4 __attribute__((ext_vector_type(4)));
typedef unsigned short u16x8 __attribute__((ext_vector_type(8)));

__device__ __forceinline__ unsigned short f2bf(float f) {
    unsigned int u = __builtin_bit_cast(unsigned int, f);
    u += 0x7FFFu + ((u >> 16) & 1u);   // round-to-nearest-even
    return (unsigned short)(u >> 16);
}

__device__ __forceinline__ float bf2f(unsigned short s) {
    return __builtin_bit_cast(float, (unsigned int)s << 16);
}

__device__ __forceinline__ f32x4 mfma_bf16(u16x8 a, u16x8 b, f32x4 c) {
    return __builtin_amdgcn_mfma_f32_16x16x32_bf16(
        __builtin_bit_cast(bf16x8, a), __builtin_bit_cast(bf16x8, b), c, 0, 0, 0);
}

// ---------------------------------------------------------------------------
// Kernel 1: qkv = xt @ W_qkv.   A = xt[t][c] (x stored [c][t]), B = W_qkv[c][n]
// Writes: Q (scaled by 0.125) [h][t][64] bf16, K [h][t][64] bf16, V^T [h][64][t] bf16
// ---------------------------------------------------------------------------
__global__ __launch_bounds__(256) void qkv_kernel(
    const float* __restrict__ x, const float* __restrict__ w,
    unsigned short* __restrict__ qws, unsigned short* __restrict__ kws,
    unsigned short* __restrict__ vtws)
{
    __shared__ __align__(16) unsigned short As[64][32];   // [m][k]
    __shared__ __align__(16) unsigned short Bs[64][32];   // [n][k]
    const int tid = threadIdx.x;
    const int t0 = blockIdx.x * 64;
    const int by = blockIdx.y;            // 0..17
    const int n0 = by * 64;
    const int lane = tid & 63;
    const int wid  = tid >> 6;
    const int wr = wid >> 1, wc = wid & 1;
    const int l15 = lane & 15, lg = lane >> 4;
    const int sm  = tid & 63;             // staging m/n index
    const int skg = tid >> 6;             // staging k-group (8 k's each)

    f32x4 acc[2][2] = {};

    for (int k0 = 0; k0 < CH; k0 += 32) {
        u16x8 av, bv;
        #pragma unroll
        for (int j = 0; j < 8; ++j) {
            av[j] = f2bf(x[(k0 + skg*8 + j) * TOK + t0 + sm]);
            bv[j] = f2bf(w[(k0 + skg*8 + j) * NQKV + n0 + sm]);
        }
        __syncthreads();
        *reinterpret_cast<u16x8*>(&As[sm][skg*8]) = av;
        *reinterpret_cast<u16x8*>(&Bs[sm][skg*8]) = bv;
        __syncthreads();

        u16x8 afr[2], bfr[2];
        #pragma unroll
        for (int mi = 0; mi < 2; ++mi)
            afr[mi] = *reinterpret_cast<const u16x8*>(&As[wr*32 + mi*16 + l15][lg*8]);
        #pragma unroll
        for (int ni = 0; ni < 2; ++ni)
            bfr[ni] = *reinterpret_cast<const u16x8*>(&Bs[wc*32 + ni*16 + l15][lg*8]);
        #pragma unroll
        for (int mi = 0; mi < 2; ++mi)
            #pragma unroll
            for (int ni = 0; ni < 2; ++ni)
                acc[mi][ni] = mfma_bf16(afr[mi], bfr[ni], acc[mi][ni]);
    }

    const float qscale = (by < 6) ? 0.125f : 1.0f;
    const int head = by % 6;
    #pragma unroll
    for (int mi = 0; mi < 2; ++mi)
    #pragma unroll
    for (int ni = 0; ni < 2; ++ni)
    #pragma unroll
    for (int r = 0; r < 4; ++r) {
        int t   = t0 + wr*32 + mi*16 + lg*4 + r;
        int dim = wc*32 + ni*16 + l15;
        unsigned short v = f2bf(acc[mi][ni][r] * qscale);
        if (by < 6)        qws[head*(TOK*HD) + t*HD + dim] = v;
        else if (by < 12)  kws[head*(TOK*HD) + t*HD + dim] = v;
        else               vtws[head*(TOK*HD) + dim*TOK + t] = v;
    }
}

// ---------------------------------------------------------------------------
// Kernel 2: flash attention with K-split. block = (q-tile 64, head, k-chunk).
// Each block walks clen keys (clen = TOK/nchunks). nchunks>1: write
// unnormalized partial O (bf16) + per-row m,l (fp32) for combine_kernel.
// nchunks==1: normalize and write directly.
// Register prefetch of next K/V tile hides global latency under compute.
// ---------------------------------------------------------------------------
__global__ __launch_bounds__(256) void attn_kernel(
    const unsigned short* __restrict__ qws, const unsigned short* __restrict__ kws,
    const unsigned short* __restrict__ vtws, unsigned short* __restrict__ odst,
    float* __restrict__ mpart, float* __restrict__ lpart,
    int clen, int nchunks)
{
    __shared__ __align__(16) unsigned short Ks[64][64];    // [ktok][d], swizzled
    __shared__ __align__(16) unsigned short Vts[64][64];   // [d][ktok], swizzled
    __shared__ __align__(16) unsigned short Ps[64][64];    // [qrow][ktok], swizzled
    const int tid = threadIdx.x;
    const int h  = blockIdx.y;
    const int q0 = blockIdx.x * 64;
    const int chunk = blockIdx.z;
    const int kbeg = chunk * clen, kend = kbeg + clen;
    const int lane = tid & 63, wid = tid >> 6;
    const int l15 = lane & 15, lg = lane >> 4;
    const int srow = tid >> 3, sch = tid & 7;   // staging: row/chunk-of-8
    const float LOG2E = 1.4426950408889634f;

    const unsigned short* qh = qws  + h*(TOK*HD);
    const unsigned short* kh = kws  + h*(TOK*HD);
    const unsigned short* vh = vtws + h*(TOK*HD);

    // Q fragments: wave's 16 rows, K-dim (=64) split into s=0,1
    u16x8 aq[2];
    #pragma unroll
    for (int s = 0; s < 2; ++s)
        aq[s] = *reinterpret_cast<const u16x8*>(
            &qh[(q0 + wid*16 + l15)*HD + s*32 + lg*8]);

    f32x4 oacc[4] = {};
    float mrow[4], lsum[4];
    #pragma unroll
    for (int r = 0; r < 4; ++r) { mrow[r] = -1e30f; lsum[r] = 0.f; }

    // prologue: prefetch first tile into registers
    u16x8 kreg[2], vreg[2];
    #pragma unroll
    for (int i = 0; i < 2; ++i) {
        int row = srow + i*32;
        kreg[i] = *reinterpret_cast<const u16x8*>(&kh[(kbeg+row)*HD + sch*8]);
        vreg[i] = *reinterpret_cast<const u16x8*>(&vh[row*TOK + kbeg + sch*8]);
    }

    for (int kt = kbeg; kt < kend; kt += 64) {
        __syncthreads();   // prev iter's reads of Ks/Vts done
        #pragma unroll
        for (int i = 0; i < 2; ++i) {
            int row = srow + i*32;
            int chs = sch ^ (row & 7);
            *reinterpret_cast<u16x8*>(&Ks[row][chs*8])  = kreg[i];
            *reinterpret_cast<u16x8*>(&Vts[row][chs*8]) = vreg[i];
        }
        // issue next-tile prefetch; latency hides under this tile's compute
        const int ktn = (kt + 64 < kend) ? (kt + 64) : kt;
        #pragma unroll
        for (int i = 0; i < 2; ++i) {
            int row = srow + i*32;
            kreg[i] = *reinterpret_cast<const u16x8*>(&kh[(ktn+row)*HD + sch*8]);
            vreg[i] = *reinterpret_cast<const u16x8*>(&vh[row*TOK + ktn + sch*8]);
        }
        __syncthreads();

        // S = Q K^T
        f32x4 sacc[4] = {};
        #pragma unroll
        for (int cf = 0; cf < 4; ++cf) {
            int row = cf*16 + l15;
            #pragma unroll
            for (int s = 0; s < 2; ++s) {
                int chs = (s*4 + lg) ^ (row & 7);
                u16x8 b = *reinterpret_cast<const u16x8*>(&Ks[row][chs*8]);
                sacc[cf] = mfma_bf16(aq[s], b, sacc[cf]);
            }
        }

        // online softmax, exp2 domain
        float sv[4][4];
        #pragma unroll
        for (int cf = 0; cf < 4; ++cf)
            #pragma unroll
            for (int r = 0; r < 4; ++r)
                sv[cf][r] = sacc[cf][r] * LOG2E;

        float tmax[4];
        #pragma unroll
        for (int r = 0; r < 4; ++r)
            tmax[r] = fmaxf(fmaxf(sv[0][r], sv[1][r]), fmaxf(sv[2][r], sv[3][r]));
        #pragma unroll
        for (int off = 1; off < 16; off <<= 1)
            #pragma unroll
            for (int r = 0; r < 4; ++r)
                tmax[r] = fmaxf(tmax[r], __shfl_xor(tmax[r], off, 64));

        float corr[4];
        #pragma unroll
        for (int r = 0; r < 4; ++r) {
            float mnew = fmaxf(mrow[r], tmax[r]);
            corr[r] = __builtin_amdgcn_exp2f(mrow[r] - mnew);
            mrow[r] = mnew;
        }
        float p[4][4], psum[4] = {0.f, 0.f, 0.f, 0.f};
        #pragma unroll
        for (int cf = 0; cf < 4; ++cf)
            #pragma unroll
            for (int r = 0; r < 4; ++r) {
                p[cf][r] = __builtin_amdgcn_exp2f(sv[cf][r] - mrow[r]);
                psum[r] += p[cf][r];
            }
        #pragma unroll
        for (int off = 1; off < 16; off <<= 1)
            #pragma unroll
            for (int r = 0; r < 4; ++r)
                psum[r] += __shfl_xor(psum[r], off, 64);
        #pragma unroll
        for (int r = 0; r < 4; ++r)
            lsum[r] = lsum[r]*corr[r] + psum[r];
        #pragma unroll
        for (int df = 0; df < 4; ++df)
            #pragma unroll
            for (int r = 0; r < 4; ++r)
                oacc[df][r] *= corr[r];

        // P -> LDS (bf16, swizzled). Rows are wave-private: no block barrier
        // needed, just drain the DS writes before re-reading.
        #pragma unroll
        for (int cf = 0; cf < 4; ++cf)
            #pragma unroll
            for (int r = 0; r < 4; ++r) {
                int row = wid*16 + lg*4 + r;
                int col = cf*16 + l15;
                int idx = ((((col >> 3) ^ (row & 7)) << 3) | (col & 7));
                Ps[row][idx] = f2bf(p[cf][r]);
            }
        asm volatile("s_waitcnt lgkmcnt(0)" ::: "memory");

        // O += P V
        u16x8 ap[2];
        {
            int prow = wid*16 + l15;
            #pragma unroll
            for (int s = 0; s < 2; ++s) {
                int chs = (s*4 + lg) ^ (prow & 7);
                ap[s] = *reinterpret_cast<const u16x8*>(&Ps[prow][chs*8]);
            }
        }
        #pragma unroll
        for (int df = 0; df < 4; ++df) {
            int vrow = df*16 + l15;
            #pragma unroll
            for (int s = 0; s < 2; ++s) {
                int chs = (s*4 + lg) ^ (vrow & 7);
                u16x8 bv = *reinterpret_cast<const u16x8*>(&Vts[vrow][chs*8]);
                oacc[df] = mfma_bf16(ap[s], bv, oacc[df]);
            }
        }
    }

    if (nchunks == 1) {
        // direct: normalize + write O bf16 [t][CH]
        #pragma unroll
        for (int df = 0; df < 4; ++df)
            #pragma unroll
            for (int r = 0; r < 4; ++r) {
                int t = q0 + wid*16 + lg*4 + r;
                int d = df*16 + l15;
                odst[t*CH + h*HD + d] = f2bf(oacc[df][r] / lsum[r]);
            }
    } else {
        // partial: unnormalized O + (m, l) per row
        const size_t cb = (size_t)(chunk*NH + h)*TOK;
        #pragma unroll
        for (int df = 0; df < 4; ++df)
            #pragma unroll
            for (int r = 0; r < 4; ++r) {
                int t = q0 + wid*16 + lg*4 + r;
                int d = df*16 + l15;
                odst[(cb + t)*HD + d] = f2bf(oacc[df][r]);
            }
        if (l15 == 0) {
            #pragma unroll
            for (int r = 0; r < 4; ++r) {
                int t = q0 + wid*16 + lg*4 + r;
                mpart[cb + t] = mrow[r];
                lpart[cb + t] = lsum[r];
            }
        }
    }
}

// ---------------------------------------------------------------------------
// Kernel 2b: combine k-chunks. One thread per (h, t, 8-wide d group).
// out = sum_c exp2(m_c - M) O_c / sum_c exp2(m_c - M) l_c
// ---------------------------------------------------------------------------
__global__ __launch_bounds__(256) void combine_kernel(
    const unsigned short* __restrict__ opart, const float* __restrict__ mpart,
    const float* __restrict__ lpart, unsigned short* __restrict__ ob, int nchunks)
{
    const int gid = blockIdx.x * 256 + threadIdx.x;  // (h, t, dg)
    const int dg = gid & 7;
    const int t  = (gid >> 3) & (TOK - 1);
    const int h  = gid >> 15;
    const int row = h*TOK + t;

    float M = -1e30f;
    for (int c = 0; c < nchunks; ++c)
        M = fmaxf(M, mpart[c*(NH*TOK) + row]);

    float wsum = 0.f;
    float o[8] = {};
    for (int c = 0; c < nchunks; ++c) {
        float wgt = __builtin_amdgcn_exp2f(mpart[c*(NH*TOK) + row] - M);
        wsum += wgt * lpart[c*(NH*TOK) + row];
        u16x8 ov = *reinterpret_cast<const u16x8*>(
            &opart[((size_t)(c*NH + h)*TOK + t)*HD + dg*8]);
        #pragma unroll
        for (int j = 0; j < 8; ++j)
            o[j] += wgt * bf2f(ov[j]);
    }
    const float inv = 1.0f / wsum;
    u16x8 res;
    #pragma unroll
    for (int j = 0; j < 8; ++j)
        res[j] = f2bf(o[j] * inv);
    *reinterpret_cast<u16x8*>(&ob[(size_t)t*CH + h*HD + dg*8]) = res;
}

// ---------------------------------------------------------------------------
// Kernel 3: out = O @ W_out + b_out, fp32 result in [t][CH] flat order
// ---------------------------------------------------------------------------
__global__ __launch_bounds__(256) void out_kernel(
    const unsigned short* __restrict__ ob, const float* __restrict__ w,
    const float* __restrict__ bias, float* __restrict__ out)
{
    __shared__ __align__(16) unsigned short As[64][32];
    __shared__ __align__(16) unsigned short Bs[64][32];
    const int tid = threadIdx.x;
    const int t0 = blockIdx.x * 64;
    const int n0 = blockIdx.y * 64;
    const int lane = tid & 63, wid = tid >> 6;
    const int wr = wid >> 1, wc = wid & 1;
    const int l15 = lane & 15, lg = lane >> 4;
    const int sm = tid & 63, skg = tid >> 6;

    f32x4 acc[2][2] = {};

    for (int k0 = 0; k0 < CH; k0 += 32) {
        u16x8 av = *reinterpret_cast<const u16x8*>(&ob[(t0+sm)*CH + k0 + skg*8]);
        u16x8 bv;
        #pragma unroll
        for (int j = 0; j < 8; ++j)
            bv[j] = f2bf(w[(k0 + skg*8 + j) * CH + n0 + sm]);
        __syncthreads();
        *reinterpret_cast<u16x8*>(&As[sm][skg*8]) = av;
        *reinterpret_cast<u16x8*>(&Bs[sm][skg*8]) = bv;
        __syncthreads();

        u16x8 afr[2], bfr[2];
        #pragma unroll
        for (int mi = 0; mi < 2; ++mi)
            afr[mi] = *reinterpret_cast<const u16x8*>(&As[wr*32 + mi*16 + l15][lg*8]);
        #pragma unroll
        for (int ni = 0; ni < 2; ++ni)
            bfr[ni] = *reinterpret_cast<const u16x8*>(&Bs[wc*32 + ni*16 + l15][lg*8]);
        #pragma unroll
        for (int mi = 0; mi < 2; ++mi)
            #pragma unroll
            for (int ni = 0; ni < 2; ++ni)
                acc[mi][ni] = mfma_bf16(afr[mi], bfr[ni], acc[mi][ni]);
    }

    #pragma unroll
    for (int mi = 0; mi < 2; ++mi)
    #pragma unroll
    for (int ni = 0; ni < 2; ++ni)
    #pragma unroll
    for (int r = 0; r < 4; ++r) {
        int t = t0 + wr*32 + mi*16 + lg*4 + r;
        int n = n0 + wc*32 + ni*16 + l15;
        out[t*CH + n] = acc[mi][ni][r] + bias[n];
    }
}

// ---------------------------------------------------------------------------
extern "C" void kernel_launch(void* const* d_in, const int* in_sizes, int n_in,
                              void* d_out, int out_size, void* d_ws, size_t ws_size,
                              hipStream_t stream) {
    const float* x    = (const float*)d_in[0];   // [384][4096] (c-major)
    const float* wqkv = (const float*)d_in[1];   // [384][1152]
    const float* wout = (const float*)d_in[2];   // [384][384]
    const float* bout = (const float*)d_in[3];   // [384]
    float* out = (float*)d_out;                  // [4096][384] flat

    // workspace layout (bf16 elems unless noted):
    //   qp, kp, vtp : NH*TOK*HD each         (Q scaled, K, V^T)
    //   op          : TOK*CH                 (attention output O)
    //   opart       : KS*NH*TOK*HD           (unnormalized partial O)
    //   mpart,lpart : KS*NH*TOK fp32 each
    unsigned short* ws  = (unsigned short*)d_ws;
    unsigned short* qp  = ws;
    unsigned short* kp  = qp + NH*TOK*HD;
    unsigned short* vtp = kp + NH*TOK*HD;
    unsigned short* op  = vtp + NH*TOK*HD;

    const size_t baseB = (size_t)(3*NH*TOK*HD + TOK*CH) * 2;
    const size_t perC  = (size_t)NH*TOK*HD*2 + (size_t)NH*TOK*2*4;
    int KS = 1;
    if      (baseB + 8*perC <= ws_size) KS = 8;
    else if (baseB + 4*perC <= ws_size) KS = 4;
    else if (baseB + 2*perC <= ws_size) KS = 2;

    qkv_kernel<<<dim3(64, 18), 256, 0, stream>>>(x, wqkv, qp, kp, vtp);

    if (KS > 1) {
        unsigned short* opart = op + (size_t)TOK*CH;
        float* mp = (float*)(opart + (size_t)KS*NH*TOK*HD);
        float* lp = mp + (size_t)KS*NH*TOK;
        attn_kernel<<<dim3(64, 6, KS), 256, 0, stream>>>(
            qp, kp, vtp, opart, mp, lp, TOK/KS, KS);
        combine_kernel<<<dim3(NH*TOK*HD/8/256), 256, 0, stream>>>(
            opart, mp, lp, op, KS);
    } else {
        attn_kernel<<<dim3(64, 6, 1), 256, 0, stream>>>(
            qp, kp, vtp, op, (float*)d_ws, (float*)d_ws, TOK, 1);
    }

    out_kernel<<<dim3(64, 6), 256, 0, stream>>>(op, wout, bout, out);
}

// Round 3
// 89.037 us; speedup vs baseline: 1.9882x; 1.4134x over previous
//
#include <hip/hip_runtime.h>
#include <hip/hip_bf16.h>

// Problem constants
#define TOK  4096      // tokens = 16*16*16
#define CH   384       // hidden
#define NH   6         // heads
#define HD   64        // head dim
#define NQKV 1152      // 3*CH

typedef __bf16 bf16x8 __attribute__((ext_vector_type(8)));
typedef float f32x4  __attribute__((ext_vector_type(4)));
typedef float f32x16 __attribute__((ext_vector_type(16)));
typedef unsigned short u16x8 __attribute__((ext_vector_type(8)));
typedef unsigned short u16x4 __attribute__((ext_vector_type(4)));
typedef unsigned int   u32x2 __attribute__((ext_vector_type(2)));
typedef unsigned int   u32x4 __attribute__((ext_vector_type(4)));

__device__ __forceinline__ unsigned short f2bf(float f) {
    unsigned int u = __builtin_bit_cast(unsigned int, f);
    u += 0x7FFFu + ((u >> 16) & 1u);   // round-to-nearest-even
    return (unsigned short)(u >> 16);
}

__device__ __forceinline__ float bf2f(unsigned short s) {
    return __builtin_bit_cast(float, (unsigned int)s << 16);
}

// pack two f32 -> one u32 of 2 bf16 (compiler folds to v_cvt_pk_bf16_f32)
__device__ __forceinline__ unsigned int pk2(float a, float b) {
    __bf16 x = (__bf16)a, y = (__bf16)b;
    unsigned short ux = __builtin_bit_cast(unsigned short, x);
    unsigned short uy = __builtin_bit_cast(unsigned short, y);
    return (unsigned int)ux | ((unsigned int)uy << 16);
}

__device__ __forceinline__ f32x4 mfma_bf16(u16x8 a, u16x8 b, f32x4 c) {
    return __builtin_amdgcn_mfma_f32_16x16x32_bf16(
        __builtin_bit_cast(bf16x8, a), __builtin_bit_cast(bf16x8, b), c, 0, 0, 0);
}

__device__ __forceinline__ f32x16 mfma32(u16x8 a, u16x8 b, f32x16 c) {
    return __builtin_amdgcn_mfma_f32_32x32x16_bf16(
        __builtin_bit_cast(bf16x8, a), __builtin_bit_cast(bf16x8, b), c, 0, 0, 0);
}

// v_permlane32_swap_b32: x.hi-lanes <-> y.lo-lanes.
// After call: x = {x@lanes0-31, y@lanes0-31}, y = {x@lanes32-63, y@lanes32-63}
__device__ __forceinline__ void plswap(unsigned int &x, unsigned int &y, int hi) {
#if __has_builtin(__builtin_amdgcn_permlane32_swap)
    u32x2 r = __builtin_amdgcn_permlane32_swap(x, y, false, false);
    x = r[0]; y = r[1];
#else
    unsigned int xs = (unsigned int)__shfl_xor((int)x, 32, 64);
    unsigned int ys = (unsigned int)__shfl_xor((int)y, 32, 64);
    unsigned int nx = hi ? ys : x;
    unsigned int ny = hi ? y  : xs;
    x = nx; y = ny;
#endif
}

// value held by lane^32 (both halves end up with the pair max/sum)
__device__ __forceinline__ float partner32(float v, int hi) {
    unsigned int a = __builtin_bit_cast(unsigned int, v);
    unsigned int b = a;
    plswap(a, b, hi);
    return __builtin_bit_cast(float, hi ? a : b);
}

// ---------------------------------------------------------------------------
// Kernel 1: qkv = xt @ W_qkv.   A = xt[t][c] (x stored [c][t]), B = W_qkv[c][n]
// Q is scaled by 0.125*log2(e) (softmax scale + exp2-domain fold; one rounding).
// Writes: Q [h][t][64], K [h][t][64], V^T [h][64][t]  (bf16)
// ---------------------------------------------------------------------------
__global__ __launch_bounds__(256) void qkv_kernel(
    const float* __restrict__ x, const float* __restrict__ w,
    unsigned short* __restrict__ qws, unsigned short* __restrict__ kws,
    unsigned short* __restrict__ vtws)
{
    __shared__ __align__(16) unsigned short As[64][32];   // [m][k]
    __shared__ __align__(16) unsigned short Bs[64][32];   // [n][k]
    const int tid = threadIdx.x;
    const int t0 = blockIdx.x * 64;
    const int by = blockIdx.y;            // 0..17
    const int n0 = by * 64;
    const int lane = tid & 63;
    const int wid  = tid >> 6;
    const int wr = wid >> 1, wc = wid & 1;
    const int l15 = lane & 15, lg = lane >> 4;
    const int sm  = tid & 63;
    const int skg = tid >> 6;

    f32x4 acc[2][2] = {};

    for (int k0 = 0; k0 < CH; k0 += 32) {
        u16x8 av, bv;
        #pragma unroll
        for (int j = 0; j < 8; ++j) {
            av[j] = f2bf(x[(k0 + skg*8 + j) * TOK + t0 + sm]);
            bv[j] = f2bf(w[(k0 + skg*8 + j) * NQKV + n0 + sm]);
        }
        __syncthreads();
        *reinterpret_cast<u16x8*>(&As[sm][skg*8]) = av;
        *reinterpret_cast<u16x8*>(&Bs[sm][skg*8]) = bv;
        __syncthreads();

        u16x8 afr[2], bfr[2];
        #pragma unroll
        for (int mi = 0; mi < 2; ++mi)
            afr[mi] = *reinterpret_cast<const u16x8*>(&As[wr*32 + mi*16 + l15][lg*8]);
        #pragma unroll
        for (int ni = 0; ni < 2; ++ni)
            bfr[ni] = *reinterpret_cast<const u16x8*>(&Bs[wc*32 + ni*16 + l15][lg*8]);
        #pragma unroll
        for (int mi = 0; mi < 2; ++mi)
            #pragma unroll
            for (int ni = 0; ni < 2; ++ni)
                acc[mi][ni] = mfma_bf16(afr[mi], bfr[ni], acc[mi][ni]);
    }

    // qscale = 0.125 * log2(e): logits come out in exp2 domain
    const float qscale = (by < 6) ? 0.18033688011112042f : 1.0f;
    const int head = by % 6;
    #pragma unroll
    for (int mi = 0; mi < 2; ++mi)
    #pragma unroll
    for (int ni = 0; ni < 2; ++ni)
    #pragma unroll
    for (int r = 0; r < 4; ++r) {
        int t   = t0 + wr*32 + mi*16 + lg*4 + r;
        int dim = wc*32 + ni*16 + l15;
        unsigned short v = f2bf(acc[mi][ni][r] * qscale);
        if (by < 6)        qws[head*(TOK*HD) + t*HD + dim] = v;
        else if (by < 12)  kws[head*(TOK*HD) + t*HD + dim] = v;
        else               vtws[head*(TOK*HD) + dim*TOK + t] = v;
    }
}

// ---------------------------------------------------------------------------
// Kernel 2: flash attention, 32x32 swapped-QK^T, in-register softmax (T12),
// defer-max (T13), reg-prefetch staging (T14). block = (128 q-rows, head,
// k-chunk); 4 waves x 32 q-rows. Each lane owns ONE q-row (col = lane&31):
//   S^T = mfma32(K, Q)  -> logits lane-local per q-row (plus partner lane^32)
//   softmax: 31 in-lane ops + 1 permlane32_swap
//   P redistribution to PV B-operand: 16 pk2 + 8 permlane32_swap (no LDS)
//   O^T = mfma32(V^T, P^T) -> rescale/normalize lane-local
// K/V tiles in LDS, XOR chunk swizzle (T2) for conflict-free ds_read_b128.
// ---------------------------------------------------------------------------
__global__ __launch_bounds__(256, 3) void attn_kernel(
    const unsigned short* __restrict__ qws, const unsigned short* __restrict__ kws,
    const unsigned short* __restrict__ vtws, unsigned short* __restrict__ odst,
    float* __restrict__ mpart, float* __restrict__ lpart,
    int clen, int nchunks)
{
    __shared__ __align__(16) unsigned short Ks[64][64];    // [ktok][d], swizzled
    __shared__ __align__(16) unsigned short Vts[64][64];   // [d][ktok], swizzled
    const int tid = threadIdx.x;
    const int h  = blockIdx.y;
    const int chunk = blockIdx.z;
    const int kbeg = chunk * clen, kend = kbeg + clen;
    const int lane = tid & 63, wid = tid >> 6;
    const int l31 = lane & 31, hi = lane >> 5;
    const int srow = tid >> 3, sch = tid & 7;
    const int qrow = blockIdx.x * 128 + wid * 32 + l31;    // this lane's q row

    const unsigned short* qh = qws  + h*(TOK*HD);
    const unsigned short* kh = kws  + h*(TOK*HD);
    const unsigned short* vh = vtws + h*(TOK*HD);

    // Q B-frags (B[d][q]: col=lane&31=q, k=d = c*16 + hi*8 + j), from global
    u16x8 qf[4];
    #pragma unroll
    for (int c = 0; c < 4; ++c)
        qf[c] = *reinterpret_cast<const u16x8*>(&qh[qrow*HD + c*16 + hi*8]);

    f32x16 oaccT[2] = {};        // O^T: [d-half]; col=q(l31), row=d_local
    float mrow = -1e30f, lsum = 0.f;

    // prologue prefetch
    u16x8 kreg[2], vreg[2];
    #pragma unroll
    for (int i = 0; i < 2; ++i) {
        int row = srow + i*32;
        kreg[i] = *reinterpret_cast<const u16x8*>(&kh[(kbeg+row)*HD + sch*8]);
        vreg[i] = *reinterpret_cast<const u16x8*>(&vh[row*TOK + kbeg + sch*8]);
    }

    for (int kt = kbeg; kt < kend; kt += 64) {
        __syncthreads();   // prev tile's LDS reads done
        #pragma unroll
        for (int i = 0; i < 2; ++i) {
            int row = srow + i*32;
            int chs = sch ^ (row & 7);
            *reinterpret_cast<u16x8*>(&Ks[row][chs*8])  = kreg[i];
            *reinterpret_cast<u16x8*>(&Vts[row][chs*8]) = vreg[i];
        }
        const int ktn = (kt + 64 < kend) ? (kt + 64) : kt;
        #pragma unroll
        for (int i = 0; i < 2; ++i) {
            int row = srow + i*32;
            kreg[i] = *reinterpret_cast<const u16x8*>(&kh[(ktn+row)*HD + sch*8]);
            vreg[i] = *reinterpret_cast<const u16x8*>(&vh[row*TOK + ktn + sch*8]);
        }
        __syncthreads();   // staging visible

        // S^T[kt][q]: A=K (row=kt_local=l31, k=d), B=Q. Chain c over D=64.
        f32x16 st[2] = {};
        #pragma unroll
        for (int g = 0; g < 2; ++g) {
            int r = g*32 + l31;
            #pragma unroll
            for (int c = 0; c < 4; ++c) {
                int chs = (c*2 + hi) ^ (r & 7);
                u16x8 kf = *reinterpret_cast<const u16x8*>(&Ks[r][chs*8]);
                st[g] = mfma32(kf, qf[c], st[g]);
            }
        }

        // row max: 31 in-lane + partner (logits already in exp2 domain)
        float tm = st[0][0];
        #pragma unroll
        for (int g = 0; g < 2; ++g)
            #pragma unroll
            for (int e = 0; e < 16; ++e)
                tm = fmaxf(tm, st[g][e]);
        tm = fmaxf(tm, partner32(tm, hi));

        // defer-max (T13): only rescale when tile max grew past threshold
        if (__any(tm > mrow + 8.0f)) {
            float mnew = fmaxf(mrow, tm);
            float corr = __builtin_amdgcn_exp2f(mrow - mnew);
            lsum *= corr;
            #pragma unroll
            for (int dh = 0; dh < 2; ++dh)
                #pragma unroll
                for (int e = 0; e < 16; ++e)
                    oaccT[dh][e] *= corr;
            mrow = mnew;
        }

        // p = exp2(s - m), row sum
        float ps = 0.f;
        #pragma unroll
        for (int g = 0; g < 2; ++g)
            #pragma unroll
            for (int e = 0; e < 16; ++e) {
                float p = __builtin_amdgcn_exp2f(st[g][e] - mrow);
                st[g][e] = p;
                ps += p;
            }
        ps += partner32(ps, hi);
        lsum += ps;

        // pack P to bf16 words: kt(g, reg=4s+m) = g*32 + 8s + m + 4*hi
        unsigned int wAw[2][4], wBw[2][4];
        #pragma unroll
        for (int g = 0; g < 2; ++g)
            #pragma unroll
            for (int s = 0; s < 4; ++s) {
                wAw[g][s] = pk2(st[g][4*s+0], st[g][4*s+1]);
                wBw[g][s] = pk2(st[g][4*s+2], st[g][4*s+3]);
            }

        // O^T += V^T P^T : per k-step, 2 permlane swaps build the P B-frag
        #pragma unroll
        for (int ks = 0; ks < 4; ++ks) {
            int g = ks >> 1, u = (ks & 1) * 2;
            unsigned int a0 = wAw[g][u], a1 = wAw[g][u+1];
            unsigned int b0 = wBw[g][u], b1 = wBw[g][u+1];
            plswap(a0, a1, hi);   // a0 -> frag word0, a1 -> word2
            plswap(b0, b1, hi);   // b0 -> word1, b1 -> word3
            u32x4 af = { a0, b0, a1, b1 };
            u16x8 pfr = __builtin_bit_cast(u16x8, af);
            #pragma unroll
            for (int dh = 0; dh < 2; ++dh) {
                int r = dh*32 + l31;
                int chs = (ks*2 + hi) ^ (r & 7);
                u16x8 vf = *reinterpret_cast<const u16x8*>(&Vts[r][chs*8]);
                oaccT[dh] = mfma32(vf, pfr, oaccT[dh]);
            }
        }
    }

    // epilogue: O^T element (dh, reg=4s+m) -> d = dh*32 + 8s + 4*hi + m, q = qrow
    if (nchunks == 1) {
        float inv = 1.0f / lsum;
        #pragma unroll
        for (int dh = 0; dh < 2; ++dh)
            #pragma unroll
            for (int s = 0; s < 4; ++s) {
                u16x4 v;
                #pragma unroll
                for (int m = 0; m < 4; ++m)
                    v[m] = f2bf(oaccT[dh][4*s+m] * inv);
                *reinterpret_cast<u16x4*>(
                    &odst[(size_t)qrow*CH + h*HD + dh*32 + s*8 + hi*4]) = v;
            }
    } else {
        const size_t cb = (size_t)(chunk*NH + h)*TOK;
        #pragma unroll
        for (int dh = 0; dh < 2; ++dh)
            #pragma unroll
            for (int s = 0; s < 4; ++s) {
                u16x4 v;
                #pragma unroll
                for (int m = 0; m < 4; ++m)
                    v[m] = f2bf(oaccT[dh][4*s+m]);
                *reinterpret_cast<u16x4*>(
                    &odst[(cb + qrow)*HD + dh*32 + s*8 + hi*4]) = v;
            }
        if (hi == 0) {
            mpart[cb + qrow] = mrow;
            lpart[cb + qrow] = lsum;
        }
    }
}

// ---------------------------------------------------------------------------
// Kernel 2b: combine k-chunks. One thread per (h, t, 8-wide d group).
// ---------------------------------------------------------------------------
__global__ __launch_bounds__(256) void combine_kernel(
    const unsigned short* __restrict__ opart, const float* __restrict__ mpart,
    const float* __restrict__ lpart, unsigned short* __restrict__ ob, int nchunks)
{
    const int gid = blockIdx.x * 256 + threadIdx.x;  // (h, t, dg)
    const int dg = gid & 7;
    const int t  = (gid >> 3) & (TOK - 1);
    const int h  = gid >> 15;
    const int row = h*TOK + t;

    float M = -1e30f;
    for (int c = 0; c < nchunks; ++c)
        M = fmaxf(M, mpart[c*(NH*TOK) + row]);

    float wsum = 0.f;
    float o[8] = {};
    for (int c = 0; c < nchunks; ++c) {
        float wgt = __builtin_amdgcn_exp2f(mpart[c*(NH*TOK) + row] - M);
        wsum += wgt * lpart[c*(NH*TOK) + row];
        u16x8 ov = *reinterpret_cast<const u16x8*>(
            &opart[((size_t)(c*NH + h)*TOK + t)*HD + dg*8]);
        #pragma unroll
        for (int j = 0; j < 8; ++j)
            o[j] += wgt * bf2f(ov[j]);
    }
    const float inv = 1.0f / wsum;
    u16x8 res;
    #pragma unroll
    for (int j = 0; j < 8; ++j)
        res[j] = f2bf(o[j] * inv);
    *reinterpret_cast<u16x8*>(&ob[(size_t)t*CH + h*HD + dg*8]) = res;
}

// ---------------------------------------------------------------------------
// Kernel 3: out = O @ W_out + b_out, fp32 result in [t][CH] flat order
// ---------------------------------------------------------------------------
__global__ __launch_bounds__(256) void out_kernel(
    const unsigned short* __restrict__ ob, const float* __restrict__ w,
    const float* __restrict__ bias, float* __restrict__ out)
{
    __shared__ __align__(16) unsigned short As[64][32];
    __shared__ __align__(16) unsigned short Bs[64][32];
    const int tid = threadIdx.x;
    const int t0 = blockIdx.x * 64;
    const int n0 = blockIdx.y * 64;
    const int lane = tid & 63, wid = tid >> 6;
    const int wr = wid >> 1, wc = wid & 1;
    const int l15 = lane & 15, lg = lane >> 4;
    const int sm = tid & 63, skg = tid >> 6;

    f32x4 acc[2][2] = {};

    for (int k0 = 0; k0 < CH; k0 += 32) {
        u16x8 av = *reinterpret_cast<const u16x8*>(&ob[(t0+sm)*CH + k0 + skg*8]);
        u16x8 bv;
        #pragma unroll
        for (int j = 0; j < 8; ++j)
            bv[j] = f2bf(w[(k0 + skg*8 + j) * CH + n0 + sm]);
        __syncthreads();
        *reinterpret_cast<u16x8*>(&As[sm][skg*8]) = av;
        *reinterpret_cast<u16x8*>(&Bs[sm][skg*8]) = bv;
        __syncthreads();

        u16x8 afr[2], bfr[2];
        #pragma unroll
        for (int mi = 0; mi < 2; ++mi)
            afr[mi] = *reinterpret_cast<const u16x8*>(&As[wr*32 + mi*16 + l15][lg*8]);
        #pragma unroll
        for (int ni = 0; ni < 2; ++ni)
            bfr[ni] = *reinterpret_cast<const u16x8*>(&Bs[wc*32 + ni*16 + l15][lg*8]);
        #pragma unroll
        for (int mi = 0; mi < 2; ++mi)
            #pragma unroll
            for (int ni = 0; ni < 2; ++ni)
                acc[mi][ni] = mfma_bf16(afr[mi], bfr[ni], acc[mi][ni]);
    }

    #pragma unroll
    for (int mi = 0; mi < 2; ++mi)
    #pragma unroll
    for (int ni = 0; ni < 2; ++ni)
    #pragma unroll
    for (int r = 0; r < 4; ++r) {
        int t = t0 + wr*32 + mi*16 + lg*4 + r;
        int n = n0 + wc*32 + ni*16 + l15;
        out[t*CH + n] = acc[mi][ni][r] + bias[n];
    }
}

// ---------------------------------------------------------------------------
extern "C" void kernel_launch(void* const* d_in, const int* in_sizes, int n_in,
                              void* d_out, int out_size, void* d_ws, size_t ws_size,
                              hipStream_t stream) {
    const float* x    = (const float*)d_in[0];   // [384][4096] (c-major)
    const float* wqkv = (const float*)d_in[1];   // [384][1152]
    const float* wout = (const float*)d_in[2];   // [384][384]
    const float* bout = (const float*)d_in[3];   // [384]
    float* out = (float*)d_out;                  // [4096][384] flat

    unsigned short* ws  = (unsigned short*)d_ws;
    unsigned short* qp  = ws;
    unsigned short* kp  = qp + NH*TOK*HD;
    unsigned short* vtp = kp + NH*TOK*HD;
    unsigned short* op  = vtp + NH*TOK*HD;

    const size_t baseB = (size_t)(3*NH*TOK*HD + TOK*CH) * 2;
    const size_t perC  = (size_t)NH*TOK*HD*2 + (size_t)NH*TOK*2*4;
    int KS = 1;
    if      (baseB + 8*perC <= ws_size) KS = 8;
    else if (baseB + 4*perC <= ws_size) KS = 4;
    else if (baseB + 2*perC <= ws_size) KS = 2;

    qkv_kernel<<<dim3(64, 18), 256, 0, stream>>>(x, wqkv, qp, kp, vtp);

    if (KS > 1) {
        unsigned short* opart = op + (size_t)TOK*CH;
        float* mp = (float*)(opart + (size_t)KS*NH*TOK*HD);
        float* lp = mp + (size_t)KS*NH*TOK;
        attn_kernel<<<dim3(TOK/128, 6, KS), 256, 0, stream>>>(
            qp, kp, vtp, opart, mp, lp, TOK/KS, KS);
        combine_kernel<<<dim3(NH*TOK*HD/8/256), 256, 0, stream>>>(
            opart, mp, lp, op, KS);
    } else {
        attn_kernel<<<dim3(TOK/128, 6, 1), 256, 0, stream>>>(
            qp, kp, vtp, op, (float*)d_ws, (float*)d_ws, TOK, 1);
    }

    out_kernel<<<dim3(64, 6), 256, 0, stream>>>(op, wout, bout, out);
}